// Round 19
// baseline (146.380 us; speedup 1.0000x reference)
//
#include <hip/hip_runtime.h>
#include <hip/hip_bf16.h>
#include <math.h>

#define B_ 4
#define S_ 2048
#define D_ 1024
#define H_ 16
#define DK_ 64

typedef __bf16 bf16;
typedef bf16 bf16x8 __attribute__((ext_vector_type(8)));
typedef float f32x4 __attribute__((ext_vector_type(4)));
typedef float f32x16 __attribute__((ext_vector_type(16)));

// XOR swizzle for [rows][64-bf16] LDS tiles (128B rows, 8x16B slots)
__device__ __forceinline__ int swz8(int row, int slot) {
    return row * 64 + ((slot ^ (row & 7)) << 3);
}
__device__ __forceinline__ unsigned packbf(float a, float b) {
    union { bf16 h[2]; unsigned u; } x;
    x.h[0] = (bf16)a; x.h[1] = (bf16)b;
    return x.u;
}
// v_permlane32_swap_b32: operands MUST be distinct values (R5 NaN bug).
__device__ __forceinline__ void permswap(unsigned& x, unsigned& y) {
    asm("v_permlane32_swap_b32 %0, %1" : "+v"(x), "+v"(y));
}
// Fast 2^x: single v_exp_f32 (TRANS pipe); inputs far from denorm edges here.
__device__ __forceinline__ float fexp2(float x) {
#if __has_builtin(__builtin_amdgcn_exp2f)
    return __builtin_amdgcn_exp2f(x);
#else
    float r;
    asm("v_exp_f32 %0, %1" : "=v"(r) : "v"(x));
    return r;
#endif
}
// async global->LDS, 16B per lane; lbase must be wave-uniform, gsrc per-lane
__device__ __forceinline__ void gld16(bf16* lbase, const bf16* gsrc) {
    __builtin_amdgcn_global_load_lds(
        (const __attribute__((address_space(1))) unsigned*)gsrc,
        (__attribute__((address_space(3))) unsigned*)lbase, 16, 0, 0);
}

// ---------------- prep: x fp32->bf16 (blocks 0..4095) + weight transpose (4096..8191) ----
// wq columns are pre-scaled by 1/sqrt(DK)*log2(e) so Q comes out of the QKV GEMM
// already in the exp2-score domain (attn then skips per-element Q scaling).
__global__ __launch_bounds__(256) void prep_kernel(const float* __restrict__ x,
                                                   const float* __restrict__ wq, const float* __restrict__ wk,
                                                   const float* __restrict__ wv, const float* __restrict__ wo,
                                                   bf16* __restrict__ xb, bf16* __restrict__ wqkvT,
                                                   bf16* __restrict__ woT) {
    __shared__ float t[32][33];
    const int bid = blockIdx.x;
    const int tid = threadIdx.x;
    if (bid < 4096) {
        const size_t i = ((size_t)bid * 256 + tid) * 8;
        const float4* src = (const float4*)(x + i);
        float4 f0 = src[0], f1 = src[1];
        bf16x8 v;
        v[0] = (bf16)f0.x; v[1] = (bf16)f0.y; v[2] = (bf16)f0.z; v[3] = (bf16)f0.w;
        v[4] = (bf16)f1.x; v[5] = (bf16)f1.y; v[6] = (bf16)f1.z; v[7] = (bf16)f1.w;
        *(bf16x8*)(xb + i) = v;
    } else {
        const int b2 = bid - 4096;
        const int z = b2 >> 10;  // 1024 blocks per matrix (32x32 tiles of 32x32)
        const float* src = (z == 0) ? wq : (z == 1) ? wk : (z == 2) ? wv : wo;
        bf16* dst = (z < 3) ? (wqkvT + (size_t)z * 1024 * 1024) : woT;
        const float s = (z == 0) ? (0.125f * 1.44269504088896340736f) : 1.0f;
        const int n0 = (b2 & 31) * 32, k0 = ((b2 >> 5) & 31) * 32;
        const int tx = tid & 31, ty = tid >> 5;  // 32 x 8
#pragma unroll
        for (int j = 0; j < 4; ++j)
            t[ty + j * 8][tx] = src[(size_t)(k0 + ty + j * 8) * 1024 + n0 + tx];
        __syncthreads();
#pragma unroll
        for (int j = 0; j < 4; ++j)
            dst[(size_t)(n0 + ty + j * 8) * 1024 + k0 + tx] = (bf16)(t[tx][ty + j * 8] * s);
    }
}

// ---------------- QKV GEMM: 128x192 tile, BK=64, 8 waves, m97 staging structure ----------
__global__ __launch_bounds__(512) void gemm_qkv_kernel(const bf16* __restrict__ A, const bf16* __restrict__ Bt,
                                                       bf16* __restrict__ Qb, bf16* __restrict__ Kb,
                                                       bf16* __restrict__ Vt) {
    __shared__ __align__(16) bf16 As[128 * 64];  // 16 KiB
    __shared__ __align__(16) bf16 Bs[192 * 64];  // 24 KiB
    const int tid = threadIdx.x;
    const int lane = tid & 63;
    const int w = tid >> 6;             // 0..7
    const int wm = w >> 2, wn = w & 3;  // wave C = 64 rows x 48 cols
    const int g = lane >> 4, r16 = lane & 15;

    // bijective XCD swizzle (1024 % 8 == 0)
    const int bid = blockIdx.x;
    const int wg = (bid & 7) * 128 + (bid >> 3);
    const int mt = wg >> 4, nt = wg & 15;
    const int m0 = mt * 128, n0 = nt * 192;

    const int srow = tid >> 3;                 // 0..63 (stripe height 64 = 0 mod 8)
    const int sslot = (tid & 7) ^ (srow & 7);
    const bf16* ga = A + (size_t)(m0 + srow) * 1024 + sslot * 8;
    const bf16* gb = Bt + (size_t)(n0 + srow) * 1024 + sslot * 8;
    const int wbase = w * 512;  // wave-uniform LDS base (elements)

    f32x4 acc[4][3] = {};

    for (int kt = 0; kt < 1024; kt += 64) {
#pragma unroll
        for (int p = 0; p < 2; ++p)
            gld16(&As[p * 4096 + wbase], ga + (size_t)p * 64 * 1024 + kt);
#pragma unroll
        for (int p = 0; p < 3; ++p)
            gld16(&Bs[p * 4096 + wbase], gb + (size_t)p * 64 * 1024 + kt);
        __syncthreads();
#pragma unroll
        for (int k0 = 0; k0 < 2; ++k0) {
            bf16x8 af[4], bfr[3];
#pragma unroll
            for (int mf = 0; mf < 4; ++mf)
                af[mf] = *(const bf16x8*)&As[swz8(wm * 64 + mf * 16 + r16, 4 * k0 + g)];
#pragma unroll
            for (int nf = 0; nf < 3; ++nf)
                bfr[nf] = *(const bf16x8*)&Bs[swz8(wn * 48 + nf * 16 + r16, 4 * k0 + g)];
#pragma unroll
            for (int mf = 0; mf < 4; ++mf)
#pragma unroll
                for (int nf = 0; nf < 3; ++nf)
                    acc[mf][nf] = __builtin_amdgcn_mfma_f32_16x16x32_bf16(af[mf], bfr[nf], acc[mf][nf], 0, 0, 0);
        }
        __syncthreads();
    }

    // epilogue: per-fragment seg: 0->Q, 1->K as [b,h,s,dk]; 2->V^T [b,h,dk,s]
#pragma unroll
    for (int mf = 0; mf < 4; ++mf) {
#pragma unroll
        for (int nf = 0; nf < 3; ++nf) {
            const int col = n0 + wn * 48 + nf * 16 + r16;
            const int seg = col >> 10;
            const int n1 = col & 1023;
            const int h = n1 >> 6, dk = n1 & 63;
            const int row0 = m0 + wm * 64 + mf * 16 + 4 * g;
            const int b = row0 >> 11, s0 = row0 & 2047;
            if (seg == 2) {
                union { bf16 h4[4]; unsigned long long u; } pk;
#pragma unroll
                for (int rr = 0; rr < 4; ++rr) pk.h4[rr] = (bf16)acc[mf][nf][rr];
                *(unsigned long long*)(Vt + (((size_t)b * H_ + h) * DK_ + dk) * S_ + s0) = pk.u;
            } else {
                bf16* dst = (seg == 0) ? Qb : Kb;
#pragma unroll
                for (int rr = 0; rr < 4; ++rr)
                    dst[(((size_t)b * H_ + h) * S_ + s0 + rr) * DK_ + dk] = (bf16)acc[mf][nf][rr];
            }
        }
    }
}

// ---------------- out-proj GEMM: 256x128 tile, 8 waves, m97 staging structure ----------
// grid 256 = exactly 1 block/CU, one uniform round. 6 loads/thread/tile for 2x the
// output of the previous 128^2 tile (8 loads) -> staging per FLOP x0.56.
__global__ __launch_bounds__(512) void gemm_out_kernel(const bf16* __restrict__ A, const bf16* __restrict__ Bt,
                                                       float* __restrict__ o0) {
    __shared__ __align__(16) bf16 As[256 * 64];  // 32 KiB
    __shared__ __align__(16) bf16 Bs[128 * 64];  // 16 KiB
    const int tid = threadIdx.x;
    const int lane = tid & 63;
    const int w = tid >> 6;             // 0..7
    const int wm = w >> 2, wn = w & 3;  // wave C = 128 rows x 32 cols
    const int g = lane >> 4, r16 = lane & 15;

    // bijective XCD swizzle (256 % 8 == 0)
    const int bid = blockIdx.x;
    const int wg = (bid & 7) * 32 + (bid >> 3);
    const int mt = wg >> 3, nt = wg & 7;
    const int m0 = mt * 256, n0 = nt * 128;

    const int srow = tid >> 3;
    const int sslot = (tid & 7) ^ (srow & 7);
    const bf16* ga = A + (size_t)(m0 + srow) * 1024 + sslot * 8;
    const bf16* gb = Bt + (size_t)(n0 + srow) * 1024 + sslot * 8;
    const int wbase = w * 512;

    f32x4 acc[8][2] = {};

    for (int kt = 0; kt < 1024; kt += 64) {
#pragma unroll
        for (int p = 0; p < 4; ++p)
            gld16(&As[p * 4096 + wbase], ga + (size_t)p * 64 * 1024 + kt);
#pragma unroll
        for (int p = 0; p < 2; ++p)
            gld16(&Bs[p * 4096 + wbase], gb + (size_t)p * 64 * 1024 + kt);
        __syncthreads();
#pragma unroll
        for (int k0 = 0; k0 < 2; ++k0) {
            bf16x8 af[8], bfr[2];
#pragma unroll
            for (int mf = 0; mf < 8; ++mf)
                af[mf] = *(const bf16x8*)&As[swz8(wm * 128 + mf * 16 + r16, 4 * k0 + g)];
#pragma unroll
            for (int nf = 0; nf < 2; ++nf)
                bfr[nf] = *(const bf16x8*)&Bs[swz8(wn * 32 + nf * 16 + r16, 4 * k0 + g)];
#pragma unroll
            for (int mf = 0; mf < 8; ++mf)
#pragma unroll
                for (int nf = 0; nf < 2; ++nf)
                    acc[mf][nf] = __builtin_amdgcn_mfma_f32_16x16x32_bf16(af[mf], bfr[nf], acc[mf][nf], 0, 0, 0);
        }
        __syncthreads();
    }

#pragma unroll
    for (int mf = 0; mf < 8; ++mf)
#pragma unroll
        for (int nf = 0; nf < 2; ++nf)
#pragma unroll
            for (int rr = 0; rr < 4; ++rr) {
                int row = m0 + wm * 128 + mf * 16 + 4 * g + rr;
                int col = n0 + wn * 32 + nf * 16 + r16;
                o0[(size_t)row * 1024 + col] = acc[mf][nf][rr];
            }
}

// ---------------- causal flash attention, swapped-operand 32x32x16, fixed-base softmax ----
// grid (64 bh, 16 qt-slots); block 256 = 4 waves. qt = QTBL[y]: equal work sums over
// each y mod 4 residue class -> balanced per-CU load under round-robin dispatch.
// Q arrives PRE-SCALED (qscale folded into wq in prep).
__global__ __launch_bounds__(256, 4) void attn_kernel(const bf16* __restrict__ Q,
                                                      const bf16* __restrict__ Kb,
                                                      const bf16* __restrict__ Vt,
                                                      bf16* __restrict__ ctx) {
    __shared__ __align__(16) bf16 lds[4][4096];  // [0..1]=K dbuf, [2..3]=V^T dbuf (32 KiB)
    const int bh = blockIdx.x;
    const int QTBL[16] = {15, 14, 13, 12, 0, 1, 2, 3, 11, 10, 9, 8, 4, 5, 6, 7};
    const int qt = QTBL[blockIdx.y];
    const int tid = threadIdx.x;
    const int lane = tid & 63, w = tid >> 6;
    const int lq = lane & 31, hi = lane >> 5;
    const int q0 = qt * 128;
    const int q0w = q0 + w * 32;
    const int q = q0w + lq;
    const int njt = 2 * qt + 2;

    const int srow = tid >> 3;
    const int sslot = (tid & 7) ^ (srow & 7);
    const bf16* kg = Kb + ((size_t)bh * S_ + srow) * DK_ + sslot * 8;
    const bf16* vg = Vt + ((size_t)bh * DK_ + srow) * S_ + sslot * 8;

    bf16x8 qf[4];
    {
        const bf16* qp = Q + ((size_t)bh * S_ + q) * DK_ + hi * 8;
#pragma unroll
        for (int kc = 0; kc < 4; ++kc) qf[kc] = *(const bf16x8*)(qp + kc * 16);
    }

    f32x16 accd[2] = {};  // O^T (unnormalized): dk = dt*32 + (r&3)+8*(r>>2)+4*hi, col q = lq
    float lsum = 0.f;     // lane-local partial (other half combined in epilogue)

    bf16x8 kreg0 = *(const bf16x8*)kg;
    bf16x8 kreg1 = *(const bf16x8*)(kg + 32 * DK_);
    bf16x8 vreg0 = *(const bf16x8*)vg;
    bf16x8 vreg1 = *(const bf16x8*)(vg + 32 * S_);

    for (int jt = 0; jt < njt; ++jt) {
        const int cur = jt & 1;
        *(bf16x8*)&lds[cur][tid * 8] = kreg0;
        *(bf16x8*)&lds[cur][tid * 8 + 2048] = kreg1;
        *(bf16x8*)&lds[2 + cur][tid * 8] = vreg0;
        *(bf16x8*)&lds[2 + cur][tid * 8 + 2048] = vreg1;
        if (jt + 1 < njt) {
            kreg0 = *(const bf16x8*)(kg + (size_t)(jt + 1) * 64 * DK_);
            kreg1 = *(const bf16x8*)(kg + (size_t)(jt + 1) * 64 * DK_ + 32 * DK_);
            vreg0 = *(const bf16x8*)(vg + (jt + 1) * 64);
            vreg1 = *(const bf16x8*)(vg + (jt + 1) * 64 + 32 * S_);
        }
        __syncthreads();

        if (jt * 64 <= q0w + 31) {
            // ---- QK^T (S^T = K @ Q^T), accumulator pre-biased to -16 ----
            f32x16 sacc[2];
#pragma unroll
            for (int c = 0; c < 2; ++c)
#pragma unroll
                for (int r = 0; r < 16; ++r) sacc[c][r] = -16.0f;
            __builtin_amdgcn_s_setprio(1);
#pragma unroll
            for (int kc = 0; kc < 4; ++kc) {
#pragma unroll
                for (int c = 0; c < 2; ++c) {
                    bf16x8 kf = *(const bf16x8*)&lds[cur][swz8(c * 32 + lq, kc * 2 + hi)];
                    sacc[c] = __builtin_amdgcn_mfma_f32_32x32x16_bf16(kf, qf[kc], sacc[c], 0, 0, 0);
                }
            }
            __builtin_amdgcn_s_setprio(0);

            // ---- causal mask (diagonal tiles only) ----
            if (jt * 64 + 63 > q0w) {
#pragma unroll
                for (int c = 0; c < 2; ++c)
#pragma unroll
                    for (int r = 0; r < 16; ++r) {
                        int key = jt * 64 + c * 32 + (r & 3) + 8 * (r >> 2) + 4 * hi;
                        if (key > q) sacc[c][r] = -INFINITY;
                    }
            }

            // ---- fixed-base softmax: P = v_exp_f32(sacc) ----
#pragma unroll
            for (int c = 0; c < 2; ++c)
#pragma unroll
                for (int r = 0; r < 16; ++r) sacc[c][r] = fexp2(sacc[c][r]);

            float s8[8];
#pragma unroll
            for (int i = 0; i < 8; ++i)
                s8[i] = (sacc[0][i] + sacc[0][i + 8]) + (sacc[1][i] + sacc[1][i + 8]);
#pragma unroll
            for (int i = 0; i < 4; ++i) s8[i] += s8[i + 4];
            lsum += (s8[0] + s8[1]) + (s8[2] + s8[3]);

            // ---- PV (O^T += V^T @ P^T), P^T frags via pack + permlane32_swap ----
#pragma unroll
            for (int kc = 0; kc < 4; ++kc) {
                const int c = kc >> 1, kf2 = kc & 1;
                unsigned w0 = packbf(sacc[c][8 * kf2 + 0], sacc[c][8 * kf2 + 1]);
                unsigned w1 = packbf(sacc[c][8 * kf2 + 2], sacc[c][8 * kf2 + 3]);
                unsigned w2 = packbf(sacc[c][8 * kf2 + 4], sacc[c][8 * kf2 + 5]);
                unsigned w3 = packbf(sacc[c][8 * kf2 + 6], sacc[c][8 * kf2 + 7]);
                permswap(w0, w2);
                permswap(w1, w3);
                union { unsigned wd[4]; bf16x8 v; } u;
                u.wd[0] = w0; u.wd[1] = w1; u.wd[2] = w2; u.wd[3] = w3;
                __builtin_amdgcn_s_setprio(1);
#pragma unroll
                for (int dt = 0; dt < 2; ++dt) {
                    bf16x8 vf = *(const bf16x8*)&lds[2 + cur][swz8(dt * 32 + lq, kc * 2 + hi)];
                    accd[dt] = __builtin_amdgcn_mfma_f32_32x32x16_bf16(vf, u.v, accd[dt], 0, 0, 0);
                }
                __builtin_amdgcn_s_setprio(0);
            }
        }
    }

    // ---- epilogue: O^T frags -> LDS (transpose) -> coalesced bf16 store ----
    __syncthreads();
    bf16* eb = &lds[0][0];
    const float rl = 1.0f / (lsum + __shfl_xor(lsum, 32));
    {
        const int rowb = (w * 32 + lq) * 128;
        const int rsw = (lq & 7) << 4;
#pragma unroll
        for (int dt = 0; dt < 2; ++dt)
#pragma unroll
            for (int rq = 0; rq < 4; ++rq) {
                union { bf16 h[4]; unsigned long long u64; } pk;
#pragma unroll
                for (int j = 0; j < 4; ++j) pk.h[j] = (bf16)(accd[dt][rq * 4 + j] * rl);
                int off = rowb + ((dt * 64 + rq * 16 + hi * 8) ^ rsw);
                *(unsigned long long*)((char*)eb + off) = pk.u64;
            }
    }
    __syncthreads();
    {
        const int row = tid >> 1, half = tid & 1;
        const int b = bh >> 4, h = bh & 15;
        bf16* op = ctx + ((size_t)b * S_ + q0 + row) * D_ + h * DK_ + half * 32;
#pragma unroll
        for (int i = 0; i < 4; ++i) {
            int sl = half * 4 + i;
            int sls = sl ^ (row & 7);
            bf16x8 v = *(const bf16x8*)((const char*)eb + row * 128 + sls * 16);
            *(bf16x8*)(op + i * 8) = v;
        }
    }
}

extern "C" void kernel_launch(void* const* d_in, const int* in_sizes, int n_in,
                              void* d_out, int out_size, void* d_ws, size_t ws_size,
                              hipStream_t stream) {
    const float* x  = (const float*)d_in[0];
    const float* wq = (const float*)d_in[1];
    const float* wk = (const float*)d_in[2];
    const float* wv = (const float*)d_in[3];
    const float* wo = (const float*)d_in[4];

    char* ws = (char*)d_ws;
    bf16* wqkvT = (bf16*)(ws);                    // 6291456 B
    bf16* woT   = (bf16*)(ws + 6291456);          // 2097152 B
    bf16* Qb    = (bf16*)(ws + 8388608);          // 16777216 B
    bf16* Kb    = (bf16*)(ws + 25165824);         // 16777216 B
    bf16* Vtb   = (bf16*)(ws + 58720256);         // 16777216 B (V^T, written by gemm_qkv)
    bf16* ctx   = (bf16*)(ws + 75497472);         // 16777216 B
    bf16* xb    = ctx;  // x-bf16 lives in the ctx region (dead until attn writes it)

    prep_kernel<<<8192, 256, 0, stream>>>(x, wq, wk, wv, wo, xb, wqkvT, woT);
    gemm_qkv_kernel<<<1024, 512, 0, stream>>>(xb, wqkvT, Qb, Kb, Vtb);
    attn_kernel<<<dim3(64, 16), 256, 0, stream>>>(Qb, Kb, Vtb, ctx);
    gemm_out_kernel<<<256, 512, 0, stream>>>(ctx, woT, (float*)d_out);
}

// Round 20
// 143.890 us; speedup vs baseline: 1.0173x; 1.0173x over previous
//
#include <hip/hip_runtime.h>
#include <hip/hip_bf16.h>
#include <math.h>

#define B_ 4
#define S_ 2048
#define D_ 1024
#define H_ 16
#define DK_ 64

typedef __bf16 bf16;
typedef bf16 bf16x8 __attribute__((ext_vector_type(8)));
typedef float f32x4 __attribute__((ext_vector_type(4)));
typedef float f32x16 __attribute__((ext_vector_type(16)));

// XOR swizzle for [rows][64-bf16] LDS tiles (128B rows, 8x16B slots)
__device__ __forceinline__ int swz8(int row, int slot) {
    return row * 64 + ((slot ^ (row & 7)) << 3);
}
__device__ __forceinline__ unsigned packbf(float a, float b) {
    union { bf16 h[2]; unsigned u; } x;
    x.h[0] = (bf16)a; x.h[1] = (bf16)b;
    return x.u;
}
// v_permlane32_swap_b32: operands MUST be distinct values (R5 NaN bug).
__device__ __forceinline__ void permswap(unsigned& x, unsigned& y) {
    asm("v_permlane32_swap_b32 %0, %1" : "+v"(x), "+v"(y));
}
// Fast 2^x: single v_exp_f32 (TRANS pipe); inputs far from denorm edges here.
__device__ __forceinline__ float fexp2(float x) {
#if __has_builtin(__builtin_amdgcn_exp2f)
    return __builtin_amdgcn_exp2f(x);
#else
    float r;
    asm("v_exp_f32 %0, %1" : "=v"(r) : "v"(x));
    return r;
#endif
}
// async global->LDS, 16B per lane; lbase must be wave-uniform, gsrc per-lane
__device__ __forceinline__ void gld16(bf16* lbase, const bf16* gsrc) {
    __builtin_amdgcn_global_load_lds(
        (const __attribute__((address_space(1))) unsigned*)gsrc,
        (__attribute__((address_space(3))) unsigned*)lbase, 16, 0, 0);
}

// ---------------- prep: x fp32->bf16 (blocks 0..4095) + weight transpose (4096..8191) ----
// wq columns are pre-scaled by 1/sqrt(DK)*log2(e) so Q comes out of the QKV GEMM
// already in the exp2-score domain (attn then skips per-element Q scaling).
__global__ __launch_bounds__(256) void prep_kernel(const float* __restrict__ x,
                                                   const float* __restrict__ wq, const float* __restrict__ wk,
                                                   const float* __restrict__ wv, const float* __restrict__ wo,
                                                   bf16* __restrict__ xb, bf16* __restrict__ wqkvT,
                                                   bf16* __restrict__ woT) {
    __shared__ float t[32][33];
    const int bid = blockIdx.x;
    const int tid = threadIdx.x;
    if (bid < 4096) {
        const size_t i = ((size_t)bid * 256 + tid) * 8;
        const float4* src = (const float4*)(x + i);
        float4 f0 = src[0], f1 = src[1];
        bf16x8 v;
        v[0] = (bf16)f0.x; v[1] = (bf16)f0.y; v[2] = (bf16)f0.z; v[3] = (bf16)f0.w;
        v[4] = (bf16)f1.x; v[5] = (bf16)f1.y; v[6] = (bf16)f1.z; v[7] = (bf16)f1.w;
        *(bf16x8*)(xb + i) = v;
    } else {
        const int b2 = bid - 4096;
        const int z = b2 >> 10;  // 1024 blocks per matrix (32x32 tiles of 32x32)
        const float* src = (z == 0) ? wq : (z == 1) ? wk : (z == 2) ? wv : wo;
        bf16* dst = (z < 3) ? (wqkvT + (size_t)z * 1024 * 1024) : woT;
        const float s = (z == 0) ? (0.125f * 1.44269504088896340736f) : 1.0f;
        const int n0 = (b2 & 31) * 32, k0 = ((b2 >> 5) & 31) * 32;
        const int tx = tid & 31, ty = tid >> 5;  // 32 x 8
#pragma unroll
        for (int j = 0; j < 4; ++j)
            t[ty + j * 8][tx] = src[(size_t)(k0 + ty + j * 8) * 1024 + n0 + tx];
        __syncthreads();
#pragma unroll
        for (int j = 0; j < 4; ++j)
            dst[(size_t)(n0 + ty + j * 8) * 1024 + k0 + tx] = (bf16)(t[tx][ty + j * 8] * s);
    }
}

// ---------------- QKV GEMM: 128x192 tile, BK=64, 8 waves, m97 staging structure ----------
__global__ __launch_bounds__(512) void gemm_qkv_kernel(const bf16* __restrict__ A, const bf16* __restrict__ Bt,
                                                       bf16* __restrict__ Qb, bf16* __restrict__ Kb,
                                                       bf16* __restrict__ Vt) {
    __shared__ __align__(16) bf16 As[128 * 64];  // 16 KiB
    __shared__ __align__(16) bf16 Bs[192 * 64];  // 24 KiB
    const int tid = threadIdx.x;
    const int lane = tid & 63;
    const int w = tid >> 6;             // 0..7
    const int wm = w >> 2, wn = w & 3;  // wave C = 64 rows x 48 cols
    const int g = lane >> 4, r16 = lane & 15;

    // bijective XCD swizzle (1024 % 8 == 0)
    const int bid = blockIdx.x;
    const int wg = (bid & 7) * 128 + (bid >> 3);
    const int mt = wg >> 4, nt = wg & 15;
    const int m0 = mt * 128, n0 = nt * 192;

    const int srow = tid >> 3;                 // 0..63 (stripe height 64 = 0 mod 8)
    const int sslot = (tid & 7) ^ (srow & 7);
    const bf16* ga = A + (size_t)(m0 + srow) * 1024 + sslot * 8;
    const bf16* gb = Bt + (size_t)(n0 + srow) * 1024 + sslot * 8;
    const int wbase = w * 512;  // wave-uniform LDS base (elements)

    f32x4 acc[4][3] = {};

    for (int kt = 0; kt < 1024; kt += 64) {
#pragma unroll
        for (int p = 0; p < 2; ++p)
            gld16(&As[p * 4096 + wbase], ga + (size_t)p * 64 * 1024 + kt);
#pragma unroll
        for (int p = 0; p < 3; ++p)
            gld16(&Bs[p * 4096 + wbase], gb + (size_t)p * 64 * 1024 + kt);
        __syncthreads();
#pragma unroll
        for (int k0 = 0; k0 < 2; ++k0) {
            bf16x8 af[4], bfr[3];
#pragma unroll
            for (int mf = 0; mf < 4; ++mf)
                af[mf] = *(const bf16x8*)&As[swz8(wm * 64 + mf * 16 + r16, 4 * k0 + g)];
#pragma unroll
            for (int nf = 0; nf < 3; ++nf)
                bfr[nf] = *(const bf16x8*)&Bs[swz8(wn * 48 + nf * 16 + r16, 4 * k0 + g)];
#pragma unroll
            for (int mf = 0; mf < 4; ++mf)
#pragma unroll
                for (int nf = 0; nf < 3; ++nf)
                    acc[mf][nf] = __builtin_amdgcn_mfma_f32_16x16x32_bf16(af[mf], bfr[nf], acc[mf][nf], 0, 0, 0);
        }
        __syncthreads();
    }

    // epilogue: per-fragment seg: 0->Q, 1->K as [b,h,s,dk]; 2->V^T [b,h,dk,s]
#pragma unroll
    for (int mf = 0; mf < 4; ++mf) {
#pragma unroll
        for (int nf = 0; nf < 3; ++nf) {
            const int col = n0 + wn * 48 + nf * 16 + r16;
            const int seg = col >> 10;
            const int n1 = col & 1023;
            const int h = n1 >> 6, dk = n1 & 63;
            const int row0 = m0 + wm * 64 + mf * 16 + 4 * g;
            const int b = row0 >> 11, s0 = row0 & 2047;
            if (seg == 2) {
                union { bf16 h4[4]; unsigned long long u; } pk;
#pragma unroll
                for (int rr = 0; rr < 4; ++rr) pk.h4[rr] = (bf16)acc[mf][nf][rr];
                *(unsigned long long*)(Vt + (((size_t)b * H_ + h) * DK_ + dk) * S_ + s0) = pk.u;
            } else {
                bf16* dst = (seg == 0) ? Qb : Kb;
#pragma unroll
                for (int rr = 0; rr < 4; ++rr)
                    dst[(((size_t)b * H_ + h) * S_ + s0 + rr) * DK_ + dk] = (bf16)acc[mf][nf][rr];
            }
        }
    }
}

// ---------------- out-proj GEMM (m97 structure, proven 22us): C fp32 = A bf16 @ Bt^T ----
__global__ __launch_bounds__(256) void gemm_out_kernel(const bf16* __restrict__ A, const bf16* __restrict__ Bt,
                                                       float* __restrict__ o0, int M, int N, int K, int NT) {
    __shared__ __align__(16) bf16 As[128 * 64];
    __shared__ __align__(16) bf16 Bs[128 * 64];
    const int tid = threadIdx.x;
    const int lane = tid & 63;
    const int w = tid >> 6;
    const int wm = w >> 1, wn = w & 1;
    const int g = lane >> 4, r16 = lane & 15;

    const int bid = blockIdx.x;
    const int qch = gridDim.x >> 3;
    const int wg = (bid & 7) * qch + (bid >> 3);
    const int mt = wg / NT, nt = wg % NT;
    const int m0 = mt * 128, n0 = nt * 128;

    const int srow = tid >> 3;
    const int sslot = (tid & 7) ^ (srow & 7);
    const bf16* ga = A + (size_t)(m0 + srow) * K + sslot * 8;
    const bf16* gb = Bt + (size_t)(n0 + srow) * K + sslot * 8;

    f32x4 acc[4][4] = {};

    for (int kt = 0; kt < K; kt += 64) {
#pragma unroll
        for (int p = 0; p < 4; ++p) {
            gld16(&As[p * 2048 + w * 512], ga + (size_t)p * 32 * K + kt);
            gld16(&Bs[p * 2048 + w * 512], gb + (size_t)p * 32 * K + kt);
        }
        __syncthreads();
#pragma unroll
        for (int k0 = 0; k0 < 2; ++k0) {
            bf16x8 af[4], bfr[4];
#pragma unroll
            for (int mf = 0; mf < 4; ++mf)
                af[mf] = *(const bf16x8*)&As[swz8(wm * 64 + mf * 16 + r16, 4 * k0 + g)];
#pragma unroll
            for (int nf = 0; nf < 4; ++nf)
                bfr[nf] = *(const bf16x8*)&Bs[swz8(wn * 64 + nf * 16 + r16, 4 * k0 + g)];
#pragma unroll
            for (int mf = 0; mf < 4; ++mf)
#pragma unroll
                for (int nf = 0; nf < 4; ++nf)
                    acc[mf][nf] = __builtin_amdgcn_mfma_f32_16x16x32_bf16(af[mf], bfr[nf], acc[mf][nf], 0, 0, 0);
        }
        __syncthreads();
    }

#pragma unroll
    for (int mf = 0; mf < 4; ++mf)
#pragma unroll
        for (int nf = 0; nf < 4; ++nf)
#pragma unroll
            for (int rr = 0; rr < 4; ++rr) {
                int row = m0 + wm * 64 + mf * 16 + 4 * g + rr;
                int col = n0 + wn * 64 + nf * 16 + r16;
                o0[(size_t)row * N + col] = acc[mf][nf][rr];
            }
}

// ---------------- causal flash attention, swapped-operand 32x32x16, fixed-base softmax ----
// grid (64 bh, 16 qt-slots); block 256 = 4 waves. qt = QTBL[y]: equal work sums over
// each y mod 4 residue class -> balanced per-CU load under round-robin dispatch.
// Q arrives PRE-SCALED (qscale folded into wq in prep).
__global__ __launch_bounds__(256, 4) void attn_kernel(const bf16* __restrict__ Q,
                                                      const bf16* __restrict__ Kb,
                                                      const bf16* __restrict__ Vt,
                                                      bf16* __restrict__ ctx) {
    __shared__ __align__(16) bf16 lds[4][4096];  // [0..1]=K dbuf, [2..3]=V^T dbuf (32 KiB)
    const int bh = blockIdx.x;
    const int QTBL[16] = {15, 14, 13, 12, 0, 1, 2, 3, 11, 10, 9, 8, 4, 5, 6, 7};
    const int qt = QTBL[blockIdx.y];
    const int tid = threadIdx.x;
    const int lane = tid & 63, w = tid >> 6;
    const int lq = lane & 31, hi = lane >> 5;
    const int q0 = qt * 128;
    const int q0w = q0 + w * 32;
    const int q = q0w + lq;
    const int njt = 2 * qt + 2;

    const int srow = tid >> 3;
    const int sslot = (tid & 7) ^ (srow & 7);
    const bf16* kg = Kb + ((size_t)bh * S_ + srow) * DK_ + sslot * 8;
    const bf16* vg = Vt + ((size_t)bh * DK_ + srow) * S_ + sslot * 8;

    bf16x8 qf[4];
    {
        const bf16* qp = Q + ((size_t)bh * S_ + q) * DK_ + hi * 8;
#pragma unroll
        for (int kc = 0; kc < 4; ++kc) qf[kc] = *(const bf16x8*)(qp + kc * 16);
    }

    f32x16 accd[2] = {};  // O^T (unnormalized): dk = dt*32 + (r&3)+8*(r>>2)+4*hi, col q = lq
    float lsum = 0.f;     // lane-local partial (other half combined in epilogue)

    bf16x8 kreg0 = *(const bf16x8*)kg;
    bf16x8 kreg1 = *(const bf16x8*)(kg + 32 * DK_);
    bf16x8 vreg0 = *(const bf16x8*)vg;
    bf16x8 vreg1 = *(const bf16x8*)(vg + 32 * S_);

    for (int jt = 0; jt < njt; ++jt) {
        const int cur = jt & 1;
        *(bf16x8*)&lds[cur][tid * 8] = kreg0;
        *(bf16x8*)&lds[cur][tid * 8 + 2048] = kreg1;
        *(bf16x8*)&lds[2 + cur][tid * 8] = vreg0;
        *(bf16x8*)&lds[2 + cur][tid * 8 + 2048] = vreg1;
        if (jt + 1 < njt) {
            kreg0 = *(const bf16x8*)(kg + (size_t)(jt + 1) * 64 * DK_);
            kreg1 = *(const bf16x8*)(kg + (size_t)(jt + 1) * 64 * DK_ + 32 * DK_);
            vreg0 = *(const bf16x8*)(vg + (jt + 1) * 64);
            vreg1 = *(const bf16x8*)(vg + (jt + 1) * 64 + 32 * S_);
        }
        __syncthreads();

        if (jt * 64 <= q0w + 31) {
            // ---- QK^T (S^T = K @ Q^T), accumulator pre-biased to -16 ----
            f32x16 sacc[2];
#pragma unroll
            for (int c = 0; c < 2; ++c)
#pragma unroll
                for (int r = 0; r < 16; ++r) sacc[c][r] = -16.0f;
            __builtin_amdgcn_s_setprio(1);
#pragma unroll
            for (int kc = 0; kc < 4; ++kc) {
#pragma unroll
                for (int c = 0; c < 2; ++c) {
                    bf16x8 kf = *(const bf16x8*)&lds[cur][swz8(c * 32 + lq, kc * 2 + hi)];
                    sacc[c] = __builtin_amdgcn_mfma_f32_32x32x16_bf16(kf, qf[kc], sacc[c], 0, 0, 0);
                }
            }
            __builtin_amdgcn_s_setprio(0);

            // ---- causal mask (diagonal tiles only) ----
            if (jt * 64 + 63 > q0w) {
#pragma unroll
                for (int c = 0; c < 2; ++c)
#pragma unroll
                    for (int r = 0; r < 16; ++r) {
                        int key = jt * 64 + c * 32 + (r & 3) + 8 * (r >> 2) + 4 * hi;
                        if (key > q) sacc[c][r] = -INFINITY;
                    }
            }

            // ---- fixed-base softmax: P = v_exp_f32(sacc) ----
#pragma unroll
            for (int c = 0; c < 2; ++c)
#pragma unroll
                for (int r = 0; r < 16; ++r) sacc[c][r] = fexp2(sacc[c][r]);

            float s8[8];
#pragma unroll
            for (int i = 0; i < 8; ++i)
                s8[i] = (sacc[0][i] + sacc[0][i + 8]) + (sacc[1][i] + sacc[1][i + 8]);
#pragma unroll
            for (int i = 0; i < 4; ++i) s8[i] += s8[i + 4];
            lsum += (s8[0] + s8[1]) + (s8[2] + s8[3]);

            // ---- PV (O^T += V^T @ P^T), P^T frags via pack + permlane32_swap ----
#pragma unroll
            for (int kc = 0; kc < 4; ++kc) {
                const int c = kc >> 1, kf2 = kc & 1;
                unsigned w0 = packbf(sacc[c][8 * kf2 + 0], sacc[c][8 * kf2 + 1]);
                unsigned w1 = packbf(sacc[c][8 * kf2 + 2], sacc[c][8 * kf2 + 3]);
                unsigned w2 = packbf(sacc[c][8 * kf2 + 4], sacc[c][8 * kf2 + 5]);
                unsigned w3 = packbf(sacc[c][8 * kf2 + 6], sacc[c][8 * kf2 + 7]);
                permswap(w0, w2);
                permswap(w1, w3);
                union { unsigned wd[4]; bf16x8 v; } u;
                u.wd[0] = w0; u.wd[1] = w1; u.wd[2] = w2; u.wd[3] = w3;
                __builtin_amdgcn_s_setprio(1);
#pragma unroll
                for (int dt = 0; dt < 2; ++dt) {
                    bf16x8 vf = *(const bf16x8*)&lds[2 + cur][swz8(dt * 32 + lq, kc * 2 + hi)];
                    accd[dt] = __builtin_amdgcn_mfma_f32_32x32x16_bf16(vf, u.v, accd[dt], 0, 0, 0);
                }
                __builtin_amdgcn_s_setprio(0);
            }
        }
    }

    // ---- epilogue: O^T frags -> LDS (transpose) -> coalesced bf16 store ----
    __syncthreads();
    bf16* eb = &lds[0][0];
    const float rl = 1.0f / (lsum + __shfl_xor(lsum, 32));
    {
        const int rowb = (w * 32 + lq) * 128;
        const int rsw = (lq & 7) << 4;
#pragma unroll
        for (int dt = 0; dt < 2; ++dt)
#pragma unroll
            for (int rq = 0; rq < 4; ++rq) {
                union { bf16 h[4]; unsigned long long u64; } pk;
#pragma unroll
                for (int j = 0; j < 4; ++j) pk.h[j] = (bf16)(accd[dt][rq * 4 + j] * rl);
                int off = rowb + ((dt * 64 + rq * 16 + hi * 8) ^ rsw);
                *(unsigned long long*)((char*)eb + off) = pk.u64;
            }
    }
    __syncthreads();
    {
        const int row = tid >> 1, half = tid & 1;
        const int b = bh >> 4, h = bh & 15;
        bf16* op = ctx + ((size_t)b * S_ + q0 + row) * D_ + h * DK_ + half * 32;
#pragma unroll
        for (int i = 0; i < 4; ++i) {
            int sl = half * 4 + i;
            int sls = sl ^ (row & 7);
            bf16x8 v = *(const bf16x8*)((const char*)eb + row * 128 + sls * 16);
            *(bf16x8*)(op + i * 8) = v;
        }
    }
}

extern "C" void kernel_launch(void* const* d_in, const int* in_sizes, int n_in,
                              void* d_out, int out_size, void* d_ws, size_t ws_size,
                              hipStream_t stream) {
    const float* x  = (const float*)d_in[0];
    const float* wq = (const float*)d_in[1];
    const float* wk = (const float*)d_in[2];
    const float* wv = (const float*)d_in[3];
    const float* wo = (const float*)d_in[4];

    char* ws = (char*)d_ws;
    bf16* wqkvT = (bf16*)(ws);                    // 6291456 B
    bf16* woT   = (bf16*)(ws + 6291456);          // 2097152 B
    bf16* Qb    = (bf16*)(ws + 8388608);          // 16777216 B
    bf16* Kb    = (bf16*)(ws + 25165824);         // 16777216 B
    bf16* Vtb   = (bf16*)(ws + 58720256);         // 16777216 B (V^T, written by gemm_qkv)
    bf16* ctx   = (bf16*)(ws + 75497472);         // 16777216 B
    bf16* xb    = ctx;  // x-bf16 lives in the ctx region (dead until attn writes it)

    prep_kernel<<<8192, 256, 0, stream>>>(x, wq, wk, wv, wo, xb, wqkvT, woT);
    gemm_qkv_kernel<<<1024, 512, 0, stream>>>(xb, wqkvT, Qb, Kb, Vtb);
    attn_kernel<<<dim3(64, 16), 256, 0, stream>>>(Qb, Kb, Vtb, ctx);
    gemm_out_kernel<<<512, 256, 0, stream>>>(ctx, woT, (float*)d_out, 8192, 1024, 1024, 8);
}

// Round 21
// 143.020 us; speedup vs baseline: 1.0235x; 1.0061x over previous
//
#include <hip/hip_runtime.h>
#include <hip/hip_bf16.h>
#include <math.h>

#define B_ 4
#define S_ 2048
#define D_ 1024
#define H_ 16
#define DK_ 64

typedef __bf16 bf16;
typedef bf16 bf16x8 __attribute__((ext_vector_type(8)));
typedef float f32x4 __attribute__((ext_vector_type(4)));
typedef float f32x16 __attribute__((ext_vector_type(16)));

// XOR swizzle for [rows][64-bf16] LDS tiles (128B rows, 8x16B slots)
__device__ __forceinline__ int swz8(int row, int slot) {
    return row * 64 + ((slot ^ (row & 7)) << 3);
}
__device__ __forceinline__ unsigned packbf(float a, float b) {
    union { bf16 h[2]; unsigned u; } x;
    x.h[0] = (bf16)a; x.h[1] = (bf16)b;
    return x.u;
}
// v_permlane32_swap_b32: operands MUST be distinct values (R5 NaN bug).
__device__ __forceinline__ void permswap(unsigned& x, unsigned& y) {
    asm("v_permlane32_swap_b32 %0, %1" : "+v"(x), "+v"(y));
}
// Fast 2^x: single v_exp_f32 (TRANS pipe); inputs far from denorm edges here.
__device__ __forceinline__ float fexp2(float x) {
#if __has_builtin(__builtin_amdgcn_exp2f)
    return __builtin_amdgcn_exp2f(x);
#else
    float r;
    asm("v_exp_f32 %0, %1" : "=v"(r) : "v"(x));
    return r;
#endif
}
// async global->LDS, 16B per lane; lbase must be wave-uniform, gsrc per-lane
__device__ __forceinline__ void gld16(bf16* lbase, const bf16* gsrc) {
    __builtin_amdgcn_global_load_lds(
        (const __attribute__((address_space(1))) unsigned*)gsrc,
        (__attribute__((address_space(3))) unsigned*)lbase, 16, 0, 0);
}

// ---------------- prep: x fp32->bf16 (blocks 0..4095) + weight transpose (4096..8191) ----
// wq columns are pre-scaled by 1/sqrt(DK)*log2(e) so Q comes out of the QKV GEMM
// already in the exp2-score domain (attn then skips per-element Q scaling).
__global__ __launch_bounds__(256) void prep_kernel(const float* __restrict__ x,
                                                   const float* __restrict__ wq, const float* __restrict__ wk,
                                                   const float* __restrict__ wv, const float* __restrict__ wo,
                                                   bf16* __restrict__ xb, bf16* __restrict__ wqkvT,
                                                   bf16* __restrict__ woT) {
    __shared__ float t[32][33];
    const int bid = blockIdx.x;
    const int tid = threadIdx.x;
    if (bid < 4096) {
        const size_t i = ((size_t)bid * 256 + tid) * 8;
        const float4* src = (const float4*)(x + i);
        float4 f0 = src[0], f1 = src[1];
        bf16x8 v;
        v[0] = (bf16)f0.x; v[1] = (bf16)f0.y; v[2] = (bf16)f0.z; v[3] = (bf16)f0.w;
        v[4] = (bf16)f1.x; v[5] = (bf16)f1.y; v[6] = (bf16)f1.z; v[7] = (bf16)f1.w;
        *(bf16x8*)(xb + i) = v;
    } else {
        const int b2 = bid - 4096;
        const int z = b2 >> 10;  // 1024 blocks per matrix (32x32 tiles of 32x32)
        const float* src = (z == 0) ? wq : (z == 1) ? wk : (z == 2) ? wv : wo;
        bf16* dst = (z < 3) ? (wqkvT + (size_t)z * 1024 * 1024) : woT;
        const float s = (z == 0) ? (0.125f * 1.44269504088896340736f) : 1.0f;
        const int n0 = (b2 & 31) * 32, k0 = ((b2 >> 5) & 31) * 32;
        const int tx = tid & 31, ty = tid >> 5;  // 32 x 8
#pragma unroll
        for (int j = 0; j < 4; ++j)
            t[ty + j * 8][tx] = src[(size_t)(k0 + ty + j * 8) * 1024 + n0 + tx];
        __syncthreads();
#pragma unroll
        for (int j = 0; j < 4; ++j)
            dst[(size_t)(n0 + ty + j * 8) * 1024 + k0 + tx] = (bf16)(t[tx][ty + j * 8] * s);
    }
}

// ---------------- QKV GEMM: 128x192 tile, BK=64, 8 waves, m97 staging structure ----------
__global__ __launch_bounds__(512) void gemm_qkv_kernel(const bf16* __restrict__ A, const bf16* __restrict__ Bt,
                                                       bf16* __restrict__ Qb, bf16* __restrict__ Kb,
                                                       bf16* __restrict__ Vt) {
    __shared__ __align__(16) bf16 As[128 * 64];  // 16 KiB
    __shared__ __align__(16) bf16 Bs[192 * 64];  // 24 KiB
    const int tid = threadIdx.x;
    const int lane = tid & 63;
    const int w = tid >> 6;             // 0..7
    const int wm = w >> 2, wn = w & 3;  // wave C = 64 rows x 48 cols
    const int g = lane >> 4, r16 = lane & 15;

    // bijective XCD swizzle (1024 % 8 == 0)
    const int bid = blockIdx.x;
    const int wg = (bid & 7) * 128 + (bid >> 3);
    const int mt = wg >> 4, nt = wg & 15;
    const int m0 = mt * 128, n0 = nt * 192;

    const int srow = tid >> 3;                 // 0..63 (stripe height 64 = 0 mod 8)
    const int sslot = (tid & 7) ^ (srow & 7);
    const bf16* ga = A + (size_t)(m0 + srow) * 1024 + sslot * 8;
    const bf16* gb = Bt + (size_t)(n0 + srow) * 1024 + sslot * 8;
    const int wbase = w * 512;  // wave-uniform LDS base (elements)

    f32x4 acc[4][3] = {};

    for (int kt = 0; kt < 1024; kt += 64) {
#pragma unroll
        for (int p = 0; p < 2; ++p)
            gld16(&As[p * 4096 + wbase], ga + (size_t)p * 64 * 1024 + kt);
#pragma unroll
        for (int p = 0; p < 3; ++p)
            gld16(&Bs[p * 4096 + wbase], gb + (size_t)p * 64 * 1024 + kt);
        __syncthreads();
#pragma unroll
        for (int k0 = 0; k0 < 2; ++k0) {
            bf16x8 af[4], bfr[3];
#pragma unroll
            for (int mf = 0; mf < 4; ++mf)
                af[mf] = *(const bf16x8*)&As[swz8(wm * 64 + mf * 16 + r16, 4 * k0 + g)];
#pragma unroll
            for (int nf = 0; nf < 3; ++nf)
                bfr[nf] = *(const bf16x8*)&Bs[swz8(wn * 48 + nf * 16 + r16, 4 * k0 + g)];
#pragma unroll
            for (int mf = 0; mf < 4; ++mf)
#pragma unroll
                for (int nf = 0; nf < 3; ++nf)
                    acc[mf][nf] = __builtin_amdgcn_mfma_f32_16x16x32_bf16(af[mf], bfr[nf], acc[mf][nf], 0, 0, 0);
        }
        __syncthreads();
    }

    // epilogue: per-fragment seg: 0->Q, 1->K as [b,h,s,dk]; 2->V^T [b,h,dk,s]
#pragma unroll
    for (int mf = 0; mf < 4; ++mf) {
#pragma unroll
        for (int nf = 0; nf < 3; ++nf) {
            const int col = n0 + wn * 48 + nf * 16 + r16;
            const int seg = col >> 10;
            const int n1 = col & 1023;
            const int h = n1 >> 6, dk = n1 & 63;
            const int row0 = m0 + wm * 64 + mf * 16 + 4 * g;
            const int b = row0 >> 11, s0 = row0 & 2047;
            if (seg == 2) {
                union { bf16 h4[4]; unsigned long long u; } pk;
#pragma unroll
                for (int rr = 0; rr < 4; ++rr) pk.h4[rr] = (bf16)acc[mf][nf][rr];
                *(unsigned long long*)(Vt + (((size_t)b * H_ + h) * DK_ + dk) * S_ + s0) = pk.u;
            } else {
                bf16* dst = (seg == 0) ? Qb : Kb;
#pragma unroll
                for (int rr = 0; rr < 4; ++rr)
                    dst[(((size_t)b * H_ + h) * S_ + s0 + rr) * DK_ + dk] = (bf16)acc[mf][nf][rr];
            }
        }
    }
}

// ---------------- out-proj GEMM (m97 structure, proven 22us): C fp32 = A bf16 @ Bt^T ----
__global__ __launch_bounds__(256) void gemm_out_kernel(const bf16* __restrict__ A, const bf16* __restrict__ Bt,
                                                       float* __restrict__ o0, int M, int N, int K, int NT) {
    __shared__ __align__(16) bf16 As[128 * 64];
    __shared__ __align__(16) bf16 Bs[128 * 64];
    const int tid = threadIdx.x;
    const int lane = tid & 63;
    const int w = tid >> 6;
    const int wm = w >> 1, wn = w & 1;
    const int g = lane >> 4, r16 = lane & 15;

    const int bid = blockIdx.x;
    const int qch = gridDim.x >> 3;
    const int wg = (bid & 7) * qch + (bid >> 3);
    const int mt = wg / NT, nt = wg % NT;
    const int m0 = mt * 128, n0 = nt * 128;

    const int srow = tid >> 3;
    const int sslot = (tid & 7) ^ (srow & 7);
    const bf16* ga = A + (size_t)(m0 + srow) * K + sslot * 8;
    const bf16* gb = Bt + (size_t)(n0 + srow) * K + sslot * 8;

    f32x4 acc[4][4] = {};

    for (int kt = 0; kt < K; kt += 64) {
#pragma unroll
        for (int p = 0; p < 4; ++p) {
            gld16(&As[p * 2048 + w * 512], ga + (size_t)p * 32 * K + kt);
            gld16(&Bs[p * 2048 + w * 512], gb + (size_t)p * 32 * K + kt);
        }
        __syncthreads();
#pragma unroll
        for (int k0 = 0; k0 < 2; ++k0) {
            bf16x8 af[4], bfr[4];
#pragma unroll
            for (int mf = 0; mf < 4; ++mf)
                af[mf] = *(const bf16x8*)&As[swz8(wm * 64 + mf * 16 + r16, 4 * k0 + g)];
#pragma unroll
            for (int nf = 0; nf < 4; ++nf)
                bfr[nf] = *(const bf16x8*)&Bs[swz8(wn * 64 + nf * 16 + r16, 4 * k0 + g)];
#pragma unroll
            for (int mf = 0; mf < 4; ++mf)
#pragma unroll
                for (int nf = 0; nf < 4; ++nf)
                    acc[mf][nf] = __builtin_amdgcn_mfma_f32_16x16x32_bf16(af[mf], bfr[nf], acc[mf][nf], 0, 0, 0);
        }
        __syncthreads();
    }

#pragma unroll
    for (int mf = 0; mf < 4; ++mf)
#pragma unroll
        for (int nf = 0; nf < 4; ++nf)
#pragma unroll
            for (int rr = 0; rr < 4; ++rr) {
                int row = m0 + wm * 64 + mf * 16 + 4 * g + rr;
                int col = n0 + wn * 64 + nf * 16 + r16;
                o0[(size_t)row * N + col] = acc[mf][nf][rr];
            }
}

// ---------------- causal flash attention, swapped-operand 32x32x16, fixed-base softmax ----
// grid (64 bh, 16 qt-slots); block 256 = 4 waves. qt = QTBL[y] (balanced per-CU load).
// Staging now via global_load_lds (linear dest + pre-swizzled source + swizzled read,
// rule #21) with double buffer and ONE barrier per tile: at tile jt the barrier both
// drains jt's loads (compiler vmcnt(0)) and releases buf[(jt+1)&1] (its readers ran
// at jt-1); then jt+1's loads issue BEFORE jt's compute so HBM latency hides under
// the MFMA+softmax phase. Removes the global->VGPR->ds_write round trip (~32 VGPR,
// 8 ds_write + waits per tile). Q arrives pre-scaled.
__global__ __launch_bounds__(256, 4) void attn_kernel(const bf16* __restrict__ Q,
                                                      const bf16* __restrict__ Kb,
                                                      const bf16* __restrict__ Vt,
                                                      bf16* __restrict__ ctx) {
    __shared__ __align__(16) bf16 lds[4][4096];  // [0..1]=K dbuf, [2..3]=V^T dbuf (32 KiB)
    const int bh = blockIdx.x;
    const int QTBL[16] = {15, 14, 13, 12, 0, 1, 2, 3, 11, 10, 9, 8, 4, 5, 6, 7};
    const int qt = QTBL[blockIdx.y];
    const int tid = threadIdx.x;
    const int lane = tid & 63, w = tid >> 6;
    const int lq = lane & 31, hi = lane >> 5;
    const int q0 = qt * 128;
    const int q0w = q0 + w * 32;
    const int q = q0w + lq;
    const int njt = 2 * qt + 2;

    // staging: chunk c = p*256+tid covers LDS 16B slot (c&7) of row (c>>3);
    // global slot pre-swizzled by the same XOR involution the reads use.
    const int srow = tid >> 3;                 // 0..31 (pass stride 32 = 0 mod 8)
    const int sslot = (tid & 7) ^ (srow & 7);
    const bf16* kg = Kb + ((size_t)bh * S_ + srow) * DK_ + sslot * 8;
    const bf16* vg = Vt + ((size_t)bh * DK_ + srow) * S_ + sslot * 8;
    const int wbase = w * 512;  // wave-uniform LDS base (elements) within a 2048-el pass

    bf16x8 qf[4];
    {
        const bf16* qp = Q + ((size_t)bh * S_ + q) * DK_ + hi * 8;
#pragma unroll
        for (int kc = 0; kc < 4; ++kc) qf[kc] = *(const bf16x8*)(qp + kc * 16);
    }

    f32x16 accd[2] = {};  // O^T (unnormalized): dk = dt*32 + (r&3)+8*(r>>2)+4*hi, col q = lq
    float lsum = 0.f;     // lane-local partial (other half combined in epilogue)

    // prologue: stage tile 0 into buf 0
#pragma unroll
    for (int p = 0; p < 2; ++p) {
        gld16(&lds[0][p * 2048 + wbase], kg + (size_t)(p * 32) * DK_);
        gld16(&lds[2][p * 2048 + wbase], vg + p * 32 * S_);
    }

    for (int jt = 0; jt < njt; ++jt) {
        const int cur = jt & 1;
        __syncthreads();  // drains tile jt's loads; buf[cur^1] readers (tile jt-1) done
        if (jt + 1 < njt) {
#pragma unroll
            for (int p = 0; p < 2; ++p) {
                gld16(&lds[cur ^ 1][p * 2048 + wbase], kg + ((size_t)(jt + 1) * 64 + p * 32) * DK_);
                gld16(&lds[2 + (cur ^ 1)][p * 2048 + wbase], vg + (jt + 1) * 64 + p * 32 * S_);
            }
        }

        if (jt * 64 <= q0w + 31) {
            // ---- QK^T (S^T = K @ Q^T), accumulator pre-biased to -16 ----
            f32x16 sacc[2];
#pragma unroll
            for (int c = 0; c < 2; ++c)
#pragma unroll
                for (int r = 0; r < 16; ++r) sacc[c][r] = -16.0f;
            __builtin_amdgcn_s_setprio(1);
#pragma unroll
            for (int kc = 0; kc < 4; ++kc) {
#pragma unroll
                for (int c = 0; c < 2; ++c) {
                    bf16x8 kf = *(const bf16x8*)&lds[cur][swz8(c * 32 + lq, kc * 2 + hi)];
                    sacc[c] = __builtin_amdgcn_mfma_f32_32x32x16_bf16(kf, qf[kc], sacc[c], 0, 0, 0);
                }
            }
            __builtin_amdgcn_s_setprio(0);

            // ---- causal mask (diagonal tiles only) ----
            if (jt * 64 + 63 > q0w) {
#pragma unroll
                for (int c = 0; c < 2; ++c)
#pragma unroll
                    for (int r = 0; r < 16; ++r) {
                        int key = jt * 64 + c * 32 + (r & 3) + 8 * (r >> 2) + 4 * hi;
                        if (key > q) sacc[c][r] = -INFINITY;
                    }
            }

            // ---- fixed-base softmax: P = v_exp_f32(sacc) ----
#pragma unroll
            for (int c = 0; c < 2; ++c)
#pragma unroll
                for (int r = 0; r < 16; ++r) sacc[c][r] = fexp2(sacc[c][r]);

            float s8[8];
#pragma unroll
            for (int i = 0; i < 8; ++i)
                s8[i] = (sacc[0][i] + sacc[0][i + 8]) + (sacc[1][i] + sacc[1][i + 8]);
#pragma unroll
            for (int i = 0; i < 4; ++i) s8[i] += s8[i + 4];
            lsum += (s8[0] + s8[1]) + (s8[2] + s8[3]);

            // ---- PV (O^T += V^T @ P^T), P^T frags via pack + permlane32_swap ----
#pragma unroll
            for (int kc = 0; kc < 4; ++kc) {
                const int c = kc >> 1, kf2 = kc & 1;
                unsigned w0 = packbf(sacc[c][8 * kf2 + 0], sacc[c][8 * kf2 + 1]);
                unsigned w1 = packbf(sacc[c][8 * kf2 + 2], sacc[c][8 * kf2 + 3]);
                unsigned w2 = packbf(sacc[c][8 * kf2 + 4], sacc[c][8 * kf2 + 5]);
                unsigned w3 = packbf(sacc[c][8 * kf2 + 6], sacc[c][8 * kf2 + 7]);
                permswap(w0, w2);
                permswap(w1, w3);
                union { unsigned wd[4]; bf16x8 v; } u;
                u.wd[0] = w0; u.wd[1] = w1; u.wd[2] = w2; u.wd[3] = w3;
                __builtin_amdgcn_s_setprio(1);
#pragma unroll
                for (int dt = 0; dt < 2; ++dt) {
                    bf16x8 vf = *(const bf16x8*)&lds[2 + cur][swz8(dt * 32 + lq, kc * 2 + hi)];
                    accd[dt] = __builtin_amdgcn_mfma_f32_32x32x16_bf16(vf, u.v, accd[dt], 0, 0, 0);
                }
                __builtin_amdgcn_s_setprio(0);
            }
        }
    }

    // ---- epilogue: O^T frags -> LDS (transpose) -> coalesced bf16 store ----
    __syncthreads();
    bf16* eb = &lds[0][0];
    const float rl = 1.0f / (lsum + __shfl_xor(lsum, 32));
    {
        const int rowb = (w * 32 + lq) * 128;
        const int rsw = (lq & 7) << 4;
#pragma unroll
        for (int dt = 0; dt < 2; ++dt)
#pragma unroll
            for (int rq = 0; rq < 4; ++rq) {
                union { bf16 h[4]; unsigned long long u64; } pk;
#pragma unroll
                for (int j = 0; j < 4; ++j) pk.h[j] = (bf16)(accd[dt][rq * 4 + j] * rl);
                int off = rowb + ((dt * 64 + rq * 16 + hi * 8) ^ rsw);
                *(unsigned long long*)((char*)eb + off) = pk.u64;
            }
    }
    __syncthreads();
    {
        const int row = tid >> 1, half = tid & 1;
        const int b = bh >> 4, h = bh & 15;
        bf16* op = ctx + ((size_t)b * S_ + q0 + row) * D_ + h * DK_ + half * 32;
#pragma unroll
        for (int i = 0; i < 4; ++i) {
            int sl = half * 4 + i;
            int sls = sl ^ (row & 7);
            bf16x8 v = *(const bf16x8*)((const char*)eb + row * 128 + sls * 16);
            *(bf16x8*)(op + i * 8) = v;
        }
    }
}

extern "C" void kernel_launch(void* const* d_in, const int* in_sizes, int n_in,
                              void* d_out, int out_size, void* d_ws, size_t ws_size,
                              hipStream_t stream) {
    const float* x  = (const float*)d_in[0];
    const float* wq = (const float*)d_in[1];
    const float* wk = (const float*)d_in[2];
    const float* wv = (const float*)d_in[3];
    const float* wo = (const float*)d_in[4];

    char* ws = (char*)d_ws;
    bf16* wqkvT = (bf16*)(ws);                    // 6291456 B
    bf16* woT   = (bf16*)(ws + 6291456);          // 2097152 B
    bf16* Qb    = (bf16*)(ws + 8388608);          // 16777216 B
    bf16* Kb    = (bf16*)(ws + 25165824);         // 16777216 B
    bf16* Vtb   = (bf16*)(ws + 58720256);         // 16777216 B (V^T, written by gemm_qkv)
    bf16* ctx   = (bf16*)(ws + 75497472);         // 16777216 B
    bf16* xb    = ctx;  // x-bf16 lives in the ctx region (dead until attn writes it)

    prep_kernel<<<8192, 256, 0, stream>>>(x, wq, wk, wv, wo, xb, wqkvT, woT);
    gemm_qkv_kernel<<<1024, 512, 0, stream>>>(xb, wqkvT, Qb, Kb, Vtb);
    attn_kernel<<<dim3(64, 16), 256, 0, stream>>>(Qb, Kb, Vtb, ctx);
    gemm_out_kernel<<<512, 256, 0, stream>>>(ctx, woT, (float*)d_out, 8192, 1024, 1024, 8);
}